// Round 16
// baseline (138.027 us; speedup 1.0000x reference)
//
#include <hip/hip_runtime.h>
#include <math.h>

typedef __attribute__((ext_vector_type(8))) short short8;
typedef __attribute__((ext_vector_type(4))) float f32x4;

namespace {
constexpr int BATCH = 4096;
constexpr int SEQT  = 256;
constexpr int INSZ  = 24;
constexpr int H     = 40;
constexpr int NOUT  = 24;
constexpr int R     = 16;    // rows per block (2 ILP groups x 8), grid = 256
constexpr int NT    = 256;   // 4 waves: 0-2 gate tiles, 3 = x-stage + FC(lagged)

__device__ __forceinline__ unsigned short f2bf(float f) {
  unsigned int u = __float_as_uint(f);
  return (unsigned short)((u + 0x7FFFu + ((u >> 16) & 1u)) >> 16);  // RNE
}
__device__ __forceinline__ unsigned short cvt_bf16(float f) {
  float r;
  asm("v_cvt_pk_bf16_f32 %0, %1, %2" : "=v"(r) : "v"(f), "v"(f));
  return (unsigned short)__float_as_uint(r);   // low 16 bits = bf16(f), RNE
}
__device__ __forceinline__ unsigned int cvt_pk2(float lo, float hi) {
  float r;
  asm("v_cvt_pk_bf16_f32 %0, %1, %2" : "=v"(r) : "v"(lo), "v"(hi));
  return __float_as_uint(r);   // {bf16(hi), bf16(lo)}
}
__device__ __forceinline__ float4 ld4(const float* p) {
  return *reinterpret_cast<const float4*>(p);
}
// Native-rate transcendentals (v_exp_f32/v_rcp_f32) — avoids IEEE div sequence.
__device__ __forceinline__ float sigm(float v) {
  return __builtin_amdgcn_rcpf(1.0f + __builtin_amdgcn_exp2f(v * -1.442695041f));
}
__device__ __forceinline__ float tanh_fast(float v) {
  return fmaf(2.0f,
              __builtin_amdgcn_rcpf(1.0f + __builtin_amdgcn_exp2f(v * -2.885390082f)),
              -1.0f);
}
}  // namespace

// Raw barrier: drain only LDS ops; global loads/stores stay in flight.
#define BAR()                                              \
  asm volatile("s_waitcnt lgkmcnt(0)" ::: "memory");       \
  __builtin_amdgcn_s_barrier();                            \
  __builtin_amdgcn_sched_barrier(0);

#define MFMA16(A, Bf, C) __builtin_amdgcn_mfma_f32_16x16x32_bf16((A), (Bf), (C), 0, 0, 0)

// In-wave ILP-2: the block's 16 rows split into two 8-row groups with separate
// double-buffered A-tiles (group g, parity p at ushort offset (g*2+p)<<10).
// Each gate wave issues BOTH groups' ds_reads, then both 7-MFMA sets, then both
// epilogues: two independent dependency chains interleave inside one in-order
// instruction stream — guaranteed latency overlap (unlike R8's lockstep TLP or
// R12's scheduler-arbitrated cross-block TLP). One barrier advances all 16 rows
// one step. Real rows of each group at A-rows lq*4+{0,1} (acc elems 0,1); pad
// rows zero forever. Zero-C MFMA chains, bias in scalar epilogue, depth-4 x
// prefetch per group (R15 trims kept).
__global__ __launch_bounds__(NT) void gru_ilp2(
    const float* __restrict__ x, const float* __restrict__ Wih,
    const float* __restrict__ Whh, const float* __restrict__ bih,
    const float* __restrict__ bhh, const float* __restrict__ Wfc,
    const float* __restrict__ bfc, float* __restrict__ out,
    float* __restrict__ hid) {
  __shared__ __align__(16) unsigned short Abuf[4 * 1024];  // 8 KB

  const int tid = threadIdx.x;
  const int l   = tid & 63;
  const int w   = tid >> 6;
  const int lm  = l & 15;
  const int lq  = l >> 4;
  const int gb0 = blockIdx.x * R;

  reinterpret_cast<uint4*>(Abuf)[tid]       = make_uint4(0, 0, 0, 0);
  reinterpret_cast<uint4*>(Abuf)[tid + 256] = make_uint4(0, 0, 0, 0);

  const int aBase0 = ((lm * 64 + lq * 8)      ^ ((lm & 7) << 3));
  const int aBase1 = ((lm * 64 + lq * 8 + 32) ^ ((lm & 7) << 3));

  // ---------------- gate role (waves 0..2) ----------------
  short8 B[4][2];
  float bias[4] = {0, 0, 0, 0};
  float hold[2][2] = {{0, 0}, {0, 0}};   // [group][elem]
  int aw[2] = {0, 0};
  int u = 0;
  bool gvalid = false;
  if (w < 3) {
    u = w * 16 + lm;
    gvalid = (u < H);
#pragma unroll
    for (int z = 0; z < 4; ++z) {
#pragma unroll
      for (int kt = 0; kt < 2; ++kt) {
        short8 b;
#pragma unroll
        for (int j = 0; j < 8; ++j) {
          const int k = kt * 32 + lq * 8 + j;
          float v = 0.0f;
          if (gvalid) {
            if (z == 0)      v = (k < 24) ? Wih[u * 24 + k]          : Whh[u * 40 + (k - 24)];
            else if (z == 1) v = (k < 24) ? Wih[(40 + u) * 24 + k]   : Whh[(40 + u) * 40 + (k - 24)];
            else if (z == 2) v = (k < 24) ? Wih[(80 + u) * 24 + k]   : 0.0f;
            else             v = (k < 24) ? 0.0f                     : Whh[(80 + u) * 40 + (k - 24)];
          }
          b[j] = (short)f2bf(v);
        }
        B[z][kt] = b;
      }
    }
    if (gvalid) {
      bias[0] = bih[u] + bhh[u];
      bias[1] = bih[40 + u] + bhh[40 + u];
      bias[2] = bih[80 + u];           // n input bias
      bias[3] = bhh[80 + u];           // n hidden bias (scaled by r)
    }
#pragma unroll
    for (int i = 0; i < 2; ++i) {
      const int arow = lq * 4 + i;     // real rows live at acc rows {0,1}
      aw[i] = ((arow * 64 + 24 + u) ^ ((arow & 7) << 3));
    }
  }

  // ---------------- x-stage + FC role (wave 3) ----------------
  short8 F[2][2];
  float biasF[2] = {0, 0};
  float* orow[2][2] = {{nullptr, nullptr}, {nullptr, nullptr}};
  const float* xpg[2] = {nullptr, nullptr};
  int xw0 = 0;
  bool xv = false;
  // depth-4 x prefetch per group: x?Qj holds x(T), T===j (mod 4)
  float4 aQ1 = make_float4(0,0,0,0), aQ2 = make_float4(0,0,0,0);
  float4 aQ3 = make_float4(0,0,0,0), aQ0 = make_float4(0,0,0,0);
  float4 bQ1 = make_float4(0,0,0,0), bQ2 = make_float4(0,0,0,0);
  float4 bQ3 = make_float4(0,0,0,0), bQ0 = make_float4(0,0,0,0);
  if (w == 3) {
#pragma unroll
    for (int f = 0; f < 2; ++f) {
      const int o = f * 16 + lm;
#pragma unroll
      for (int kt = 0; kt < 2; ++kt) {
        short8 b;
#pragma unroll
        for (int j = 0; j < 8; ++j) {
          const int k = kt * 32 + lq * 8 + j;
          const float v = (o < NOUT && k >= 24) ? Wfc[o * H + (k - 24)] : 0.0f;
          b[j] = (short)f2bf(v);
        }
        F[f][kt] = b;
      }
      biasF[f] = (o < NOUT) ? bfc[o] : 0.0f;
    }
#pragma unroll
    for (int g = 0; g < 2; ++g)
#pragma unroll
      for (int i = 0; i < 2; ++i)
        orow[g][i] = out + ((size_t)(gb0 + g * 8 + lq * 2 + i) * SEQT) * NOUT;

    // x staging: per group 48 float4 chunks (8 rows x 6), lanes l<48
    xv = (l < 48);
    const int xr = l / 6, xc = (l - xr * 6) * 4;
    const int ar_ = ((xr >> 1) << 2) + (xr & 1);
    if (xv) {
      xpg[0] = x + ((size_t)(gb0 + xr) * SEQT) * INSZ + xc;
      xpg[1] = x + ((size_t)(gb0 + 8 + xr) * SEQT) * INSZ + xc;
    }
    xw0 = ((ar_ * 64 + xc) ^ ((ar_ & 7) << 3));
  }

  const f32x4 kZero = {0.0f, 0.0f, 0.0f, 0.0f};

  __syncthreads();  // zero-init visible

  if (w == 3 && xv) {  // stage x(0) both groups into parity-0; prefetch x(1..4)
    const float4 v0 = ld4(xpg[0]);
    *reinterpret_cast<uint2*>(&Abuf[xw0]) =
        make_uint2(cvt_pk2(v0.x, v0.y), cvt_pk2(v0.z, v0.w));
    const float4 v1 = ld4(xpg[1]);
    *reinterpret_cast<uint2*>(&Abuf[2048 + xw0]) =
        make_uint2(cvt_pk2(v1.x, v1.y), cvt_pk2(v1.z, v1.w));
    aQ1 = ld4(xpg[0] + 1 * INSZ);  bQ1 = ld4(xpg[1] + 1 * INSZ);
    aQ2 = ld4(xpg[0] + 2 * INSZ);  bQ2 = ld4(xpg[1] + 2 * INSZ);
    aQ3 = ld4(xpg[0] + 3 * INSZ);  bQ3 = ld4(xpg[1] + 3 * INSZ);
    aQ0 = ld4(xpg[0] + 4 * INSZ);  bQ0 = ld4(xpg[1] + 4 * INSZ);
  }
  __syncthreads();  // x(0) staged

// Both groups' gate steps, chains interleaved: all 4 ds_reads first, then the
// two 7-MFMA sets, then the two scalar epilogues. BO/NBO are group-0 offsets;
// group 1 adds 2048.
#define GATE2(BO, NBO)                                                          \
  if (w < 3) {                                                                  \
    const short8 A00 = *reinterpret_cast<const short8*>(&Abuf[(BO) + aBase0]);  \
    const short8 A01 = *reinterpret_cast<const short8*>(&Abuf[(BO) + aBase1]);  \
    const short8 A10 = *reinterpret_cast<const short8*>(&Abuf[2048 + (BO) + aBase0]); \
    const short8 A11 = *reinterpret_cast<const short8*>(&Abuf[2048 + (BO) + aBase1]); \
    f32x4 ar0 = MFMA16(A00, B[0][0], kZero);                                    \
    f32x4 az0 = MFMA16(A00, B[1][0], kZero);                                    \
    f32x4 ax0 = MFMA16(A00, B[2][0], kZero);                                    \
    f32x4 ah0 = MFMA16(A00, B[3][0], kZero);                                    \
    f32x4 ar1 = MFMA16(A10, B[0][0], kZero);                                    \
    f32x4 az1 = MFMA16(A10, B[1][0], kZero);                                    \
    f32x4 ax1 = MFMA16(A10, B[2][0], kZero);                                    \
    f32x4 ah1 = MFMA16(A10, B[3][0], kZero);                                    \
    ar0 = MFMA16(A01, B[0][1], ar0);                                            \
    az0 = MFMA16(A01, B[1][1], az0);                                            \
    ah0 = MFMA16(A01, B[3][1], ah0);                                            \
    ar1 = MFMA16(A11, B[0][1], ar1);                                            \
    az1 = MFMA16(A11, B[1][1], az1);                                            \
    ah1 = MFMA16(A11, B[3][1], ah1);                                            \
    _Pragma("unroll")                                                           \
    for (int i = 0; i < 2; ++i) {                                               \
      const float rr = sigm(ar0[i] + bias[0]);                                  \
      const float zz = sigm(az0[i] + bias[1]);                                  \
      const float nn = tanh_fast(fmaf(rr, ah0[i] + bias[3], ax0[i] + bias[2])); \
      const float h  = fmaf(zz, hold[0][i] - nn, nn);                           \
      hold[0][i] = h;                                                           \
      if (gvalid) Abuf[(NBO) + aw[i]] = cvt_bf16(h);                            \
    }                                                                           \
    _Pragma("unroll")                                                           \
    for (int i = 0; i < 2; ++i) {                                               \
      const float rr = sigm(ar1[i] + bias[0]);                                  \
      const float zz = sigm(az1[i] + bias[1]);                                  \
      const float nn = tanh_fast(fmaf(rr, ah1[i] + bias[3], ax1[i] + bias[2])); \
      const float h  = fmaf(zz, hold[1][i] - nn, nn);                           \
      hold[1][i] = h;                                                           \
      if (gvalid) Abuf[2048 + (NBO) + aw[i]] = cvt_bf16(h);                     \
    }                                                                           \
  }

// stage x(T) (both groups) into parity buffer TBO; reload regs <- x(T+4)
#define XSTAGE2(T, TBO, XSa, XSb)                                               \
  if (xv) {                                                                     \
    if ((T) < SEQT) {                                                           \
      *reinterpret_cast<uint2*>(&Abuf[(TBO) + xw0]) =                           \
          make_uint2(cvt_pk2(XSa.x, XSa.y), cvt_pk2(XSa.z, XSa.w));             \
      *reinterpret_cast<uint2*>(&Abuf[2048 + (TBO) + xw0]) =                    \
          make_uint2(cvt_pk2(XSb.x, XSb.y), cvt_pk2(XSb.z, XSb.w));             \
    }                                                                           \
    if ((T) + 4 < SEQT) {                                                       \
      XSa = ld4(xpg[0] + (size_t)((T) + 4) * INSZ);                             \
      XSb = ld4(xpg[1] + (size_t)((T) + 4) * INSZ);                             \
    }                                                                           \
  }

// FC for step T (both groups), reading parity buffer BO (holds h(T))
#define FC2(T, BO)                                                              \
  {                                                                             \
    const short8 hA00 = *reinterpret_cast<const short8*>(&Abuf[(BO) + aBase0]); \
    const short8 hA01 = *reinterpret_cast<const short8*>(&Abuf[(BO) + aBase1]); \
    const short8 hA10 = *reinterpret_cast<const short8*>(&Abuf[2048 + (BO) + aBase0]); \
    const short8 hA11 = *reinterpret_cast<const short8*>(&Abuf[2048 + (BO) + aBase1]); \
    f32x4 f00 = MFMA16(hA00, F[0][0], kZero);                                   \
    f32x4 f01 = MFMA16(hA00, F[1][0], kZero);                                   \
    f32x4 f10 = MFMA16(hA10, F[0][0], kZero);                                   \
    f32x4 f11 = MFMA16(hA10, F[1][0], kZero);                                   \
    f00 = MFMA16(hA01, F[0][1], f00);                                           \
    f01 = MFMA16(hA01, F[1][1], f01);                                           \
    f10 = MFMA16(hA11, F[0][1], f10);                                           \
    f11 = MFMA16(hA11, F[1][1], f11);                                           \
    _Pragma("unroll")                                                           \
    for (int i = 0; i < 2; ++i) {                                               \
      orow[0][i][(size_t)(T) * NOUT + lm] = sigm(f00[i] + biasF[0]);            \
      orow[1][i][(size_t)(T) * NOUT + lm] = sigm(f10[i] + biasF[0]);            \
      if (lm < 8) {                                                             \
        orow[0][i][(size_t)(T) * NOUT + 16 + lm] = sigm(f01[i] + biasF[1]);     \
        orow[1][i][(size_t)(T) * NOUT + 16 + lm] = sigm(f11[i] + biasF[1]);     \
      }                                                                         \
    }                                                                           \
  }

  for (int tt = 0; tt < SEQT; tt += 4) {
    // ---- interval tt: parity bo=0, nbo=1024 ----
    GATE2(0, 1024)
    if (w == 3) {
      XSTAGE2(tt + 1, 1024, aQ1, bQ1)
      if (tt > 0) FC2(tt - 1, 0)
    }
    BAR()
    // ---- interval tt+1: bo=1024, nbo=0 ----
    GATE2(1024, 0)
    if (w == 3) {
      XSTAGE2(tt + 2, 0, aQ2, bQ2)
      FC2(tt, 1024)
    }
    BAR()
    // ---- interval tt+2 ----
    GATE2(0, 1024)
    if (w == 3) {
      XSTAGE2(tt + 3, 1024, aQ3, bQ3)
      FC2(tt + 1, 0)
    }
    BAR()
    // ---- interval tt+3 ----
    GATE2(1024, 0)
    if (w == 3) {
      XSTAGE2(tt + 4, 0, aQ0, bQ0)
      FC2(tt + 2, 1024)
    }
    BAR()
  }
  // epilogue: FC for the final step (h(255) lives in parity 0)
  if (w == 3) FC2(SEQT - 1, 0)

  // final hidden state from registers (2 groups x 2 real rows per lane)
  if (w < 3 && gvalid) {
#pragma unroll
    for (int g = 0; g < 2; ++g)
#pragma unroll
      for (int i = 0; i < 2; ++i)
        hid[(size_t)(gb0 + g * 8 + lq * 2 + i) * H + u] = hold[g][i];
  }
}

extern "C" void kernel_launch(void* const* d_in, const int* in_sizes, int n_in,
                              void* d_out, int out_size, void* d_ws, size_t ws_size,
                              hipStream_t stream) {
  const float* x   = (const float*)d_in[0];
  const float* Wih = (const float*)d_in[1];
  const float* Whh = (const float*)d_in[2];
  const float* bih = (const float*)d_in[3];
  const float* bhh = (const float*)d_in[4];
  const float* Wfc = (const float*)d_in[5];
  const float* bfc = (const float*)d_in[6];
  float* out = (float*)d_out;
  float* hid = out + (size_t)BATCH * SEQT * NOUT;

  dim3 grid(BATCH / R);
  dim3 block(NT);
  hipLaunchKernelGGL(gru_ilp2, grid, block, 0, stream,
                     x, Wih, Whh, bih, bhh, Wfc, bfc, out, hid);
}

// Round 17
// 135.388 us; speedup vs baseline: 1.0195x; 1.0195x over previous
//
#include <hip/hip_runtime.h>
#include <math.h>

typedef __attribute__((ext_vector_type(8))) short short8;
typedef __attribute__((ext_vector_type(4))) float f32x4;

namespace {
constexpr int BATCH = 4096;
constexpr int SEQT  = 256;
constexpr int INSZ  = 24;
constexpr int H     = 40;
constexpr int NOUT  = 24;
constexpr int R     = 8;     // rows per block (2 ILP groups x 4), grid = 512 (2 blocks/CU)
constexpr int NT    = 256;   // 4 waves: 0-2 gate tiles, 3 = x-stage + FC(lagged)

__device__ __forceinline__ unsigned short f2bf(float f) {
  unsigned int u = __float_as_uint(f);
  return (unsigned short)((u + 0x7FFFu + ((u >> 16) & 1u)) >> 16);  // RNE
}
__device__ __forceinline__ unsigned short cvt_bf16(float f) {
  float r;
  asm("v_cvt_pk_bf16_f32 %0, %1, %2" : "=v"(r) : "v"(f), "v"(f));
  return (unsigned short)__float_as_uint(r);   // low 16 bits = bf16(f), RNE
}
__device__ __forceinline__ unsigned int cvt_pk2(float lo, float hi) {
  float r;
  asm("v_cvt_pk_bf16_f32 %0, %1, %2" : "=v"(r) : "v"(lo), "v"(hi));
  return __float_as_uint(r);   // {bf16(hi), bf16(lo)}
}
__device__ __forceinline__ float4 ld4(const float* p) {
  return *reinterpret_cast<const float4*>(p);
}
// Native-rate transcendentals (v_exp_f32/v_rcp_f32) — avoids IEEE div sequence.
__device__ __forceinline__ float sigm(float v) {
  return __builtin_amdgcn_rcpf(1.0f + __builtin_amdgcn_exp2f(v * -1.442695041f));
}
__device__ __forceinline__ float tanh_fast(float v) {
  return fmaf(2.0f,
              __builtin_amdgcn_rcpf(1.0f + __builtin_amdgcn_exp2f(v * -2.885390082f)),
              -1.0f);
}
}  // namespace

// Raw barrier: drain only LDS ops; global loads/stores stay in flight.
#define BAR()                                              \
  asm volatile("s_waitcnt lgkmcnt(0)" ::: "memory");       \
  __builtin_amdgcn_s_barrier();                            \
  __builtin_amdgcn_sched_barrier(0);

#define MFMA16(A, Bf, C) __builtin_amdgcn_mfma_f32_16x16x32_bf16((A), (Bf), (C), 0, 0, 0)

// Untested quadrant of {blocks/CU} x {in-wave ILP}: 2 independent 8-row blocks
// per CU (proven sweet spot, R12/R15), each block internally ILP-2 over two
// 4-row groups with separate double-buffered A-tiles (buffer (g*2+p)<<10).
// Gate waves issue 4 ds_reads, then two independent 7-MFMA chains, then two
// 1-item epilogues — in-stream overlap (R16) on top of cross-block overlap
// (R12). Real rows of group g at A-rows lq*4 (acc elem 0); batch row =
// gb0 + g*4 + lq. Per-CU VALU work unchanged vs R15; MFMA x2 (free at 11%).
// Zero-C MFMA chains, bias in epilogue, depth-4 x prefetch (R15 trims kept).
__global__ __launch_bounds__(NT) void gru_q4(
    const float* __restrict__ x, const float* __restrict__ Wih,
    const float* __restrict__ Whh, const float* __restrict__ bih,
    const float* __restrict__ bhh, const float* __restrict__ Wfc,
    const float* __restrict__ bfc, float* __restrict__ out,
    float* __restrict__ hid) {
  __shared__ __align__(16) unsigned short Abuf[4 * 1024];  // 8 KB

  const int tid = threadIdx.x;
  const int l   = tid & 63;
  const int w   = tid >> 6;
  const int lm  = l & 15;
  const int lq  = l >> 4;
  const int gb0 = blockIdx.x * R;

  reinterpret_cast<uint4*>(Abuf)[tid]       = make_uint4(0, 0, 0, 0);
  reinterpret_cast<uint4*>(Abuf)[tid + 256] = make_uint4(0, 0, 0, 0);

  const int aBase0 = ((lm * 64 + lq * 8)      ^ ((lm & 7) << 3));
  const int aBase1 = ((lm * 64 + lq * 8 + 32) ^ ((lm & 7) << 3));

  // ---------------- gate role (waves 0..2) ----------------
  short8 B[4][2];
  float bias[4] = {0, 0, 0, 0};
  float hold[2] = {0, 0};            // [group], elem 0 only
  int aw0 = 0;
  int u = 0;
  bool gvalid = false;
  if (w < 3) {
    u = w * 16 + lm;
    gvalid = (u < H);
#pragma unroll
    for (int z = 0; z < 4; ++z) {
#pragma unroll
      for (int kt = 0; kt < 2; ++kt) {
        short8 b;
#pragma unroll
        for (int j = 0; j < 8; ++j) {
          const int k = kt * 32 + lq * 8 + j;
          float v = 0.0f;
          if (gvalid) {
            if (z == 0)      v = (k < 24) ? Wih[u * 24 + k]          : Whh[u * 40 + (k - 24)];
            else if (z == 1) v = (k < 24) ? Wih[(40 + u) * 24 + k]   : Whh[(40 + u) * 40 + (k - 24)];
            else if (z == 2) v = (k < 24) ? Wih[(80 + u) * 24 + k]   : 0.0f;
            else             v = (k < 24) ? 0.0f                     : Whh[(80 + u) * 40 + (k - 24)];
          }
          b[j] = (short)f2bf(v);
        }
        B[z][kt] = b;
      }
    }
    if (gvalid) {
      bias[0] = bih[u] + bhh[u];
      bias[1] = bih[40 + u] + bhh[40 + u];
      bias[2] = bih[80 + u];           // n input bias
      bias[3] = bhh[80 + u];           // n hidden bias (scaled by r)
    }
    {
      const int arow = lq * 4;         // real row of this lane (acc elem 0)
      aw0 = ((arow * 64 + 24 + u) ^ ((arow & 7) << 3));
    }
  }

  // ---------------- x-stage + FC role (wave 3) ----------------
  short8 F[2][2];
  float biasF[2] = {0, 0};
  float* orow[2] = {nullptr, nullptr};   // [group]: row gb0 + g*4 + lq
  const float* xp0 = nullptr;
  int xwBase = 0;                        // includes group buffer base
  bool xv = false;
  // depth-4 x prefetch: xQj holds x(T) with T === j (mod 4)
  float4 xQ1 = make_float4(0,0,0,0), xQ2 = make_float4(0,0,0,0);
  float4 xQ3 = make_float4(0,0,0,0), xQ0 = make_float4(0,0,0,0);
  if (w == 3) {
#pragma unroll
    for (int f = 0; f < 2; ++f) {
      const int o = f * 16 + lm;
#pragma unroll
      for (int kt = 0; kt < 2; ++kt) {
        short8 b;
#pragma unroll
        for (int j = 0; j < 8; ++j) {
          const int k = kt * 32 + lq * 8 + j;
          const float v = (o < NOUT && k >= 24) ? Wfc[o * H + (k - 24)] : 0.0f;
          b[j] = (short)f2bf(v);
        }
        F[f][kt] = b;
      }
      biasF[f] = (o < NOUT) ? bfc[o] : 0.0f;
    }
#pragma unroll
    for (int g = 0; g < 2; ++g)
      orow[g] = out + ((size_t)(gb0 + g * 4 + lq) * SEQT) * NOUT;

    // x staging: 48 lanes; l<24 -> group 0, 24<=l<48 -> group 1.
    // Within group: 4 rows x 6 float4 chunks; row r -> A-row 4r.
    xv = (l < 48);
    const int g  = l / 24;
    const int m  = l - g * 24;
    const int xr = m / 6, xc = (m - xr * 6) * 4;
    const int ar_ = xr << 2;
    if (xv) xp0 = x + ((size_t)(gb0 + g * 4 + xr) * SEQT) * INSZ + xc;
    xwBase = (g << 11) + ((ar_ * 64 + xc) ^ ((ar_ & 7) << 3));
  }

  // persistent zero C for all MFMAs
  const f32x4 kZero = {0.0f, 0.0f, 0.0f, 0.0f};

  __syncthreads();  // zero-init visible

  if (w == 3 && xv) {  // stage x(0) into parity-0; prefetch x(1..4)
    const float4 v0 = ld4(xp0);
    *reinterpret_cast<uint2*>(&Abuf[xwBase]) =
        make_uint2(cvt_pk2(v0.x, v0.y), cvt_pk2(v0.z, v0.w));
    xQ1 = ld4(xp0 + 1 * INSZ);
    xQ2 = ld4(xp0 + 2 * INSZ);
    xQ3 = ld4(xp0 + 3 * INSZ);
    xQ0 = ld4(xp0 + 4 * INSZ);
  }
  __syncthreads();  // x(0) staged

// Both groups' 7-MFMA gate steps interleaved (independent chains); zero-C,
// bias in epilogue on the single real elem per group. BO/NBO are parity
// offsets (0/1024); group 1 adds 2048.
#define GATE2(BO, NBO)                                                          \
  if (w < 3) {                                                                  \
    const short8 A00 = *reinterpret_cast<const short8*>(&Abuf[(BO) + aBase0]);  \
    const short8 A01 = *reinterpret_cast<const short8*>(&Abuf[(BO) + aBase1]);  \
    const short8 A10 = *reinterpret_cast<const short8*>(&Abuf[2048 + (BO) + aBase0]); \
    const short8 A11 = *reinterpret_cast<const short8*>(&Abuf[2048 + (BO) + aBase1]); \
    f32x4 ar0 = MFMA16(A00, B[0][0], kZero);                                    \
    f32x4 az0 = MFMA16(A00, B[1][0], kZero);                                    \
    f32x4 ax0 = MFMA16(A00, B[2][0], kZero);                                    \
    f32x4 ah0 = MFMA16(A00, B[3][0], kZero);                                    \
    f32x4 ar1 = MFMA16(A10, B[0][0], kZero);                                    \
    f32x4 az1 = MFMA16(A10, B[1][0], kZero);                                    \
    f32x4 ax1 = MFMA16(A10, B[2][0], kZero);                                    \
    f32x4 ah1 = MFMA16(A10, B[3][0], kZero);                                    \
    ar0 = MFMA16(A01, B[0][1], ar0);                                            \
    az0 = MFMA16(A01, B[1][1], az0);                                            \
    ah0 = MFMA16(A01, B[3][1], ah0);                                            \
    ar1 = MFMA16(A11, B[0][1], ar1);                                            \
    az1 = MFMA16(A11, B[1][1], az1);                                            \
    ah1 = MFMA16(A11, B[3][1], ah1);                                            \
    {                                                                           \
      const float rr = sigm(ar0[0] + bias[0]);                                  \
      const float zz = sigm(az0[0] + bias[1]);                                  \
      const float nn = tanh_fast(fmaf(rr, ah0[0] + bias[3], ax0[0] + bias[2])); \
      const float h  = fmaf(zz, hold[0] - nn, nn);                              \
      hold[0] = h;                                                              \
      if (gvalid) Abuf[(NBO) + aw0] = cvt_bf16(h);                              \
    }                                                                           \
    {                                                                           \
      const float rr = sigm(ar1[0] + bias[0]);                                  \
      const float zz = sigm(az1[0] + bias[1]);                                  \
      const float nn = tanh_fast(fmaf(rr, ah1[0] + bias[3], ax1[0] + bias[2])); \
      const float h  = fmaf(zz, hold[1] - nn, nn);                              \
      hold[1] = h;                                                              \
      if (gvalid) Abuf[2048 + (NBO) + aw0] = cvt_bf16(h);                       \
    }                                                                           \
  }

// stage x(T) into parity buffer TBO (lane's own group); reload XS <- x(T+4)
#define XSTAGE(T, TBO, XS)                                                      \
  if (xv) {                                                                     \
    if ((T) < SEQT) {                                                           \
      *reinterpret_cast<uint2*>(&Abuf[(TBO) + xwBase]) =                        \
          make_uint2(cvt_pk2(XS.x, XS.y), cvt_pk2(XS.z, XS.w));                 \
    }                                                                           \
    if ((T) + 4 < SEQT) XS = ld4(xp0 + (size_t)((T) + 4) * INSZ);               \
  }

// FC for step T (both groups), reading parity buffer BO (holds h(T))
#define FC2(T, BO)                                                              \
  {                                                                             \
    const short8 hA00 = *reinterpret_cast<const short8*>(&Abuf[(BO) + aBase0]); \
    const short8 hA01 = *reinterpret_cast<const short8*>(&Abuf[(BO) + aBase1]); \
    const short8 hA10 = *reinterpret_cast<const short8*>(&Abuf[2048 + (BO) + aBase0]); \
    const short8 hA11 = *reinterpret_cast<const short8*>(&Abuf[2048 + (BO) + aBase1]); \
    f32x4 f00 = MFMA16(hA00, F[0][0], kZero);                                   \
    f32x4 f01 = MFMA16(hA00, F[1][0], kZero);                                   \
    f32x4 f10 = MFMA16(hA10, F[0][0], kZero);                                   \
    f32x4 f11 = MFMA16(hA10, F[1][0], kZero);                                   \
    f00 = MFMA16(hA01, F[0][1], f00);                                           \
    f01 = MFMA16(hA01, F[1][1], f01);                                           \
    f10 = MFMA16(hA11, F[0][1], f10);                                           \
    f11 = MFMA16(hA11, F[1][1], f11);                                           \
    orow[0][(size_t)(T) * NOUT + lm] = sigm(f00[0] + biasF[0]);                 \
    orow[1][(size_t)(T) * NOUT + lm] = sigm(f10[0] + biasF[0]);                 \
    if (lm < 8) {                                                               \
      orow[0][(size_t)(T) * NOUT + 16 + lm] = sigm(f01[0] + biasF[1]);          \
      orow[1][(size_t)(T) * NOUT + 16 + lm] = sigm(f11[0] + biasF[1]);          \
    }                                                                           \
  }

  for (int tt = 0; tt < SEQT; tt += 4) {
    // ---- interval tt: parity bo=0, nbo=1024 ----
    GATE2(0, 1024)
    if (w == 3) {
      XSTAGE(tt + 1, 1024, xQ1)
      if (tt > 0) FC2(tt - 1, 0)
    }
    BAR()
    // ---- interval tt+1: bo=1024, nbo=0 ----
    GATE2(1024, 0)
    if (w == 3) {
      XSTAGE(tt + 2, 0, xQ2)
      FC2(tt, 1024)
    }
    BAR()
    // ---- interval tt+2 ----
    GATE2(0, 1024)
    if (w == 3) {
      XSTAGE(tt + 3, 1024, xQ3)
      FC2(tt + 1, 0)
    }
    BAR()
    // ---- interval tt+3 ----
    GATE2(1024, 0)
    if (w == 3) {
      XSTAGE(tt + 4, 0, xQ0)
      FC2(tt + 2, 1024)
    }
    BAR()
  }
  // epilogue: FC for the final step (h(255) lives in parity 0)
  if (w == 3) FC2(SEQT - 1, 0)

  // final hidden state from registers (1 real row per lane per group)
  if (w < 3 && gvalid) {
#pragma unroll
    for (int g = 0; g < 2; ++g)
      hid[(size_t)(gb0 + g * 4 + lq) * H + u] = hold[g];
  }
}

extern "C" void kernel_launch(void* const* d_in, const int* in_sizes, int n_in,
                              void* d_out, int out_size, void* d_ws, size_t ws_size,
                              hipStream_t stream) {
  const float* x   = (const float*)d_in[0];
  const float* Wih = (const float*)d_in[1];
  const float* Whh = (const float*)d_in[2];
  const float* bih = (const float*)d_in[3];
  const float* bhh = (const float*)d_in[4];
  const float* Wfc = (const float*)d_in[5];
  const float* bfc = (const float*)d_in[6];
  float* out = (float*)d_out;
  float* hid = out + (size_t)BATCH * SEQT * NOUT;

  dim3 grid(BATCH / R);
  dim3 block(NT);
  hipLaunchKernelGGL(gru_q4, grid, block, 0, stream,
                     x, Wih, Whh, bih, bhh, Wfc, bfc, out, hid);
}